// Round 4
// baseline (86.977 us; speedup 1.0000x reference)
//
#include <hip/hip_runtime.h>
#include <math.h>

// HyperConnections: out[(b*S+t), n, d] = sum_s M[t][s] * in[(b*S+s), n, d]
// M[t][s] = sinkhorn(H_res/tau)[s][t] + softmax(H_post)[t] * softmax(H_pre)[s]
//
// B=4, S=4, N=2048, D=1024, fp32. Memory-bound: 128 MiB in + 128 MiB out.
// Single kernel: every thread redundantly computes the 4x4 mix matrix with
// fast-math intrinsics (~0.4us dependent chain, no sync/LDS/extra launch),
// then streams 2 float4-quads x 4 streams.

#define HC_S 4
#define HC_TAU 0.05f
#define HC_ITERS 10

typedef float f4 __attribute__((ext_vector_type(4)));

// N*D/4 float4 elements per stream = 2048*1024/4 = 524288 = 2^19
constexpr int ND4 = (2048 * 1024) / 4;
constexpr int ND4_SHIFT = 19;
constexpr int TOTAL = 4 * ND4;     // quad-groups (each covers all 4 streams)
constexpr int QPT = 2;             // quads per thread per stream

__device__ inline float lse4_fast(float a, float b, float c, float d) {
    float m = fmaxf(fmaxf(a, b), fmaxf(c, d));
    return m + __logf(__expf(a - m) + __expf(b - m) + __expf(c - m) + __expf(d - m));
}

__global__ __launch_bounds__(256) void hc_mix_kernel(
    const f4* __restrict__ in, f4* __restrict__ out,
    const float* __restrict__ Hres, const float* __restrict__ Hpre,
    const float* __restrict__ Hpost)
{
    // ---- redundant per-thread preamble (uniform -> scalar loads) ----
    float Z[HC_S][HC_S], u[HC_S], v[HC_S];
    #pragma unroll
    for (int i = 0; i < HC_S; ++i) { u[i] = 0.f; v[i] = 0.f; }
    #pragma unroll
    for (int i = 0; i < HC_S; ++i)
        #pragma unroll
        for (int j = 0; j < HC_S; ++j)
            Z[i][j] = Hres[i * HC_S + j] * (1.0f / HC_TAU);

    for (int it = 0; it < HC_ITERS; ++it) {
        #pragma unroll
        for (int i = 0; i < HC_S; ++i)
            u[i] = -lse4_fast(Z[i][0] + v[0], Z[i][1] + v[1],
                              Z[i][2] + v[2], Z[i][3] + v[3]);
        #pragma unroll
        for (int j = 0; j < HC_S; ++j)
            v[j] = -lse4_fast(Z[0][j] + u[0], Z[1][j] + u[1],
                              Z[2][j] + u[2], Z[3][j] + u[3]);
    }

    float hp[HC_S];
    float m = fmaxf(fmaxf(Hpre[0], Hpre[1]), fmaxf(Hpre[2], Hpre[3]));
    float ssum = 0.f;
    #pragma unroll
    for (int s = 0; s < HC_S; ++s) { hp[s] = __expf(Hpre[s] - m); ssum += hp[s]; }
    float inv = 1.0f / ssum;
    #pragma unroll
    for (int s = 0; s < HC_S; ++s) hp[s] *= inv;

    float bt[HC_S];
    m = fmaxf(fmaxf(Hpost[0], Hpost[1]), fmaxf(Hpost[2], Hpost[3]));
    ssum = 0.f;
    #pragma unroll
    for (int t = 0; t < HC_S; ++t) { bt[t] = __expf(Hpost[t] - m); ssum += bt[t]; }
    inv = 1.0f / ssum;
    #pragma unroll
    for (int t = 0; t < HC_S; ++t) bt[t] *= inv;

    float M[16];
    #pragma unroll
    for (int t = 0; t < HC_S; ++t)
        #pragma unroll
        for (int s = 0; s < HC_S; ++s)
            M[t * HC_S + s] = __expf(Z[s][t] + u[s] + v[t]) + bt[t] * hp[s];

    // ---- streaming mix: QPT quads x 4 streams in, 4 streams out ----
    // Block covers 256*QPT consecutive quads; thread t handles quads
    // blockStart + t + k*256 (k=0..QPT-1). All accesses wave-coalesced.
    int blockStart = blockIdx.x * (256 * QPT);
    int i0 = blockStart + threadIdx.x;
    int b = i0 >> ND4_SHIFT;          // batch (block never straddles: 512 | 2^19)
    size_t sbase = (size_t)(b * 4) << ND4_SHIFT;

    f4 q[QPT][4];
    #pragma unroll
    for (int k = 0; k < QPT; ++k) {
        size_t base = sbase + (size_t)((i0 + k * 256) & (ND4 - 1));
        q[k][0] = in[base];
        q[k][1] = in[base + ND4];
        q[k][2] = in[base + 2 * ND4];
        q[k][3] = in[base + 3 * ND4];
    }

    #pragma unroll
    for (int k = 0; k < QPT; ++k) {
        size_t base = sbase + (size_t)((i0 + k * 256) & (ND4 - 1));
        #pragma unroll
        for (int t = 0; t < 4; ++t) {
            f4 o;
            o.x = M[4*t+0]*q[k][0].x + M[4*t+1]*q[k][1].x + M[4*t+2]*q[k][2].x + M[4*t+3]*q[k][3].x;
            o.y = M[4*t+0]*q[k][0].y + M[4*t+1]*q[k][1].y + M[4*t+2]*q[k][2].y + M[4*t+3]*q[k][3].y;
            o.z = M[4*t+0]*q[k][0].z + M[4*t+1]*q[k][1].z + M[4*t+2]*q[k][2].z + M[4*t+3]*q[k][3].z;
            o.w = M[4*t+0]*q[k][0].w + M[4*t+1]*q[k][1].w + M[4*t+2]*q[k][2].w + M[4*t+3]*q[k][3].w;
            out[base + (size_t)t * ND4] = o;
        }
    }
}

extern "C" void kernel_launch(void* const* d_in, const int* in_sizes, int n_in,
                              void* d_out, int out_size, void* d_ws, size_t ws_size,
                              hipStream_t stream) {
    const f4* in       = (const f4*)d_in[0];
    const float* Hres  = (const float*)d_in[1];
    const float* Hpre  = (const float*)d_in[2];
    const float* Hpost = (const float*)d_in[3];
    f4* out = (f4*)d_out;

    // TOTAL/(256*QPT) = 4096 blocks, one pass, no grid-stride.
    hc_mix_kernel<<<TOTAL / (256 * QPT), 256, 0, stream>>>(in, out, Hres, Hpre, Hpost);
}

// Round 5
// 55.277 us; speedup vs baseline: 1.5735x; 1.5735x over previous
//
#include <hip/hip_runtime.h>
#include <math.h>

// HyperConnections: out[(b*S+t), n, d] = sum_s M[t][s] * in[(b*S+s), n, d]
// M[t][s] = sinkhorn(H_res/tau)[s][t] + softmax(H_post)[t] * softmax(H_pre)[s]
//
// B=4, S=4, N=2048, D=1024, fp32. Memory-bound: 128 MiB in + 128 MiB out.
// Thread 0 of each block computes the 4x4 mix matrix with fast-math
// intrinsics (short dependent chain, charged once per block), broadcasts
// via LDS; all threads then stream float4 quads (4 in -> 4 out).

#define HC_S 4
#define HC_TAU 0.05f
#define HC_ITERS 10

typedef float f4 __attribute__((ext_vector_type(4)));

// N*D/4 float4 elements per stream = 2048*1024/4 = 524288 = 2^19
constexpr int ND4 = (2048 * 1024) / 4;
constexpr int ND4_SHIFT = 19;
constexpr int TOTAL = 4 * ND4; // B * ND4 work items (each covers all 4 streams)

__device__ inline float lse4_fast(float a, float b, float c, float d) {
    float m = fmaxf(fmaxf(a, b), fmaxf(c, d));
    return m + __logf(__expf(a - m) + __expf(b - m) + __expf(c - m) + __expf(d - m));
}

__global__ __launch_bounds__(256) void hc_mix_kernel(
    const f4* __restrict__ in, f4* __restrict__ out,
    const float* __restrict__ Hres, const float* __restrict__ Hpre,
    const float* __restrict__ Hpost)
{
    __shared__ float Ms[16];

    if (threadIdx.x == 0) {
        // --- log-domain Sinkhorn on 4x4 (10 iters, tau=0.05), fast-math ---
        float Z[HC_S][HC_S], u[HC_S], v[HC_S];
        #pragma unroll
        for (int i = 0; i < HC_S; ++i) { u[i] = 0.f; v[i] = 0.f; }
        #pragma unroll
        for (int i = 0; i < HC_S; ++i)
            #pragma unroll
            for (int j = 0; j < HC_S; ++j)
                Z[i][j] = Hres[i * HC_S + j] * (1.0f / HC_TAU);

        for (int it = 0; it < HC_ITERS; ++it) {
            #pragma unroll
            for (int i = 0; i < HC_S; ++i)
                u[i] = -lse4_fast(Z[i][0] + v[0], Z[i][1] + v[1],
                                  Z[i][2] + v[2], Z[i][3] + v[3]);
            #pragma unroll
            for (int j = 0; j < HC_S; ++j)
                v[j] = -lse4_fast(Z[0][j] + u[0], Z[1][j] + u[1],
                                  Z[2][j] + u[2], Z[3][j] + u[3]);
        }

        // --- softmax(H_pre), softmax(H_post) ---
        float hp[HC_S];
        float m = fmaxf(fmaxf(Hpre[0], Hpre[1]), fmaxf(Hpre[2], Hpre[3]));
        float ssum = 0.f;
        #pragma unroll
        for (int s = 0; s < HC_S; ++s) { hp[s] = __expf(Hpre[s] - m); ssum += hp[s]; }
        float inv = 1.0f / ssum;
        #pragma unroll
        for (int s = 0; s < HC_S; ++s) hp[s] *= inv;

        float bt[HC_S];
        m = fmaxf(fmaxf(Hpost[0], Hpost[1]), fmaxf(Hpost[2], Hpost[3]));
        ssum = 0.f;
        #pragma unroll
        for (int t = 0; t < HC_S; ++t) { bt[t] = __expf(Hpost[t] - m); ssum += bt[t]; }
        inv = 1.0f / ssum;
        #pragma unroll
        for (int t = 0; t < HC_S; ++t) bt[t] *= inv;

        // M[t][s] = h_res[s][t] + beta[t]*h_pre[s]; h_res[s][t]=exp(Z[s][t]+u[s]+v[t])
        #pragma unroll
        for (int t = 0; t < HC_S; ++t)
            #pragma unroll
            for (int s = 0; s < HC_S; ++s)
                Ms[t * HC_S + s] = __expf(Z[s][t] + u[s] + v[t]) + bt[t] * hp[s];
    }
    __syncthreads();

    float M[16];
    #pragma unroll
    for (int k = 0; k < 16; ++k) M[k] = Ms[k];

    // --- grid-stride mix: 4 stream loads -> 4 stream stores, float4 each ---
    for (int i = blockIdx.x * blockDim.x + threadIdx.x; i < TOTAL;
         i += gridDim.x * blockDim.x) {
        int b = i >> ND4_SHIFT;          // batch index
        int r = i & (ND4 - 1);           // position within (n,d) plane
        size_t base = ((size_t)(b * 4) << ND4_SHIFT) + (size_t)r;

        f4 v0 = in[base];
        f4 v1 = in[base + ND4];
        f4 v2 = in[base + 2 * ND4];
        f4 v3 = in[base + 3 * ND4];

        #pragma unroll
        for (int t = 0; t < 4; ++t) {
            f4 o;
            o.x = M[4*t+0] * v0.x + M[4*t+1] * v1.x + M[4*t+2] * v2.x + M[4*t+3] * v3.x;
            o.y = M[4*t+0] * v0.y + M[4*t+1] * v1.y + M[4*t+2] * v2.y + M[4*t+3] * v3.y;
            o.z = M[4*t+0] * v0.z + M[4*t+1] * v1.z + M[4*t+2] * v2.z + M[4*t+3] * v3.z;
            o.w = M[4*t+0] * v0.w + M[4*t+1] * v1.w + M[4*t+2] * v2.w + M[4*t+3] * v3.w;
            out[base + (size_t)t * ND4] = o;
        }
    }
}

extern "C" void kernel_launch(void* const* d_in, const int* in_sizes, int n_in,
                              void* d_out, int out_size, void* d_ws, size_t ws_size,
                              hipStream_t stream) {
    const f4* in       = (const f4*)d_in[0];
    const float* Hres  = (const float*)d_in[1];
    const float* Hpre  = (const float*)d_in[2];
    const float* Hpost = (const float*)d_in[3];
    f4* out = (f4*)d_out;

    // 2048 blocks x 256 threads: 4 grid-stride iterations per thread.
    hc_mix_kernel<<<2048, 256, 0, stream>>>(in, out, Hres, Hpre, Hpost);
}

// Round 6
// 48.375 us; speedup vs baseline: 1.7980x; 1.1427x over previous
//
#include <hip/hip_runtime.h>
#include <math.h>

// HyperConnections: out[(b*S+t), n, d] = sum_s M[t][s] * in[(b*S+s), n, d]
// M[t][s] = sinkhorn(H_res/tau)[s][t] + softmax(H_post)[t] * softmax(H_pre)[s]
//
// B=4, S=4, N=2048, D=1024, fp32. Memory-bound: 128 MiB in + 128 MiB out.
// Structure: each thread owns one r in [0, N*D/4) and processes all 4 batches.
// Batch-0 loads are issued BEFORE the thread-0 Sinkhorn preamble so HBM
// latency hides the dependent chain; batch b+1 loads are prefetched before
// batch b's compute/stores (software pipeline).

#define HC_S 4
#define HC_TAU 0.05f
#define HC_ITERS 10

typedef float f4 __attribute__((ext_vector_type(4)));

// N*D/4 float4 elements per stream = 2048*1024/4 = 524288 = 2^19
constexpr int ND4 = (2048 * 1024) / 4;
constexpr size_t BATCH_STRIDE = (size_t)4 * ND4;   // 4 streams per batch

__device__ inline float lse4_fast(float a, float b, float c, float d) {
    float m = fmaxf(fmaxf(a, b), fmaxf(c, d));
    return m + __logf(__expf(a - m) + __expf(b - m) + __expf(c - m) + __expf(d - m));
}

__global__ __launch_bounds__(256) void hc_mix_kernel(
    const f4* __restrict__ in, f4* __restrict__ out,
    const float* __restrict__ Hres, const float* __restrict__ Hpre,
    const float* __restrict__ Hpost)
{
    __shared__ float Ms[16];

    const size_t r = (size_t)blockIdx.x * 256 + threadIdx.x;   // 0 .. ND4-1

    // ---- issue batch-0 loads first: overlap HBM latency with preamble ----
    f4 cur0 = in[r];
    f4 cur1 = in[r + ND4];
    f4 cur2 = in[r + 2 * ND4];
    f4 cur3 = in[r + 3 * ND4];

    if (threadIdx.x == 0) {
        // --- log-domain Sinkhorn on 4x4 (10 iters, tau=0.05), fast-math ---
        float Z[HC_S][HC_S], u[HC_S], v[HC_S];
        #pragma unroll
        for (int i = 0; i < HC_S; ++i) { u[i] = 0.f; v[i] = 0.f; }
        #pragma unroll
        for (int i = 0; i < HC_S; ++i)
            #pragma unroll
            for (int j = 0; j < HC_S; ++j)
                Z[i][j] = Hres[i * HC_S + j] * (1.0f / HC_TAU);

        for (int it = 0; it < HC_ITERS; ++it) {
            #pragma unroll
            for (int i = 0; i < HC_S; ++i)
                u[i] = -lse4_fast(Z[i][0] + v[0], Z[i][1] + v[1],
                                  Z[i][2] + v[2], Z[i][3] + v[3]);
            #pragma unroll
            for (int j = 0; j < HC_S; ++j)
                v[j] = -lse4_fast(Z[0][j] + u[0], Z[1][j] + u[1],
                                  Z[2][j] + u[2], Z[3][j] + u[3]);
        }

        float hp[HC_S];
        float m = fmaxf(fmaxf(Hpre[0], Hpre[1]), fmaxf(Hpre[2], Hpre[3]));
        float ssum = 0.f;
        #pragma unroll
        for (int s = 0; s < HC_S; ++s) { hp[s] = __expf(Hpre[s] - m); ssum += hp[s]; }
        float inv = 1.0f / ssum;
        #pragma unroll
        for (int s = 0; s < HC_S; ++s) hp[s] *= inv;

        float bt[HC_S];
        m = fmaxf(fmaxf(Hpost[0], Hpost[1]), fmaxf(Hpost[2], Hpost[3]));
        ssum = 0.f;
        #pragma unroll
        for (int t = 0; t < HC_S; ++t) { bt[t] = __expf(Hpost[t] - m); ssum += bt[t]; }
        inv = 1.0f / ssum;
        #pragma unroll
        for (int t = 0; t < HC_S; ++t) bt[t] *= inv;

        // M[t][s] = h_res[s][t] + beta[t]*h_pre[s]; h_res[s][t]=exp(Z[s][t]+u[s]+v[t])
        #pragma unroll
        for (int t = 0; t < HC_S; ++t)
            #pragma unroll
            for (int s = 0; s < HC_S; ++s)
                Ms[t * HC_S + s] = __expf(Z[s][t] + u[s] + v[t]) + bt[t] * hp[s];
    }
    __syncthreads();

    float M[16];
    #pragma unroll
    for (int k = 0; k < 16; ++k) M[k] = Ms[k];

    // ---- 4-batch software pipeline: prefetch b+1, compute/store b ----
    #pragma unroll
    for (int b = 0; b < 4; ++b) {
        f4 n0, n1, n2, n3;
        if (b < 3) {
            const f4* pn = in + (size_t)(b + 1) * BATCH_STRIDE + r;
            n0 = pn[0];
            n1 = pn[ND4];
            n2 = pn[2 * ND4];
            n3 = pn[3 * ND4];
        }

        f4* po = out + (size_t)b * BATCH_STRIDE + r;
        #pragma unroll
        for (int t = 0; t < 4; ++t) {
            f4 o;
            o.x = M[4*t+0]*cur0.x + M[4*t+1]*cur1.x + M[4*t+2]*cur2.x + M[4*t+3]*cur3.x;
            o.y = M[4*t+0]*cur0.y + M[4*t+1]*cur1.y + M[4*t+2]*cur2.y + M[4*t+3]*cur3.y;
            o.z = M[4*t+0]*cur0.z + M[4*t+1]*cur1.z + M[4*t+2]*cur2.z + M[4*t+3]*cur3.z;
            o.w = M[4*t+0]*cur0.w + M[4*t+1]*cur1.w + M[4*t+2]*cur2.w + M[4*t+3]*cur3.w;
            po[(size_t)t * ND4] = o;
        }

        if (b < 3) { cur0 = n0; cur1 = n1; cur2 = n2; cur3 = n3; }
    }
}

extern "C" void kernel_launch(void* const* d_in, const int* in_sizes, int n_in,
                              void* d_out, int out_size, void* d_ws, size_t ws_size,
                              hipStream_t stream) {
    const f4* in       = (const f4*)d_in[0];
    const float* Hres  = (const float*)d_in[1];
    const float* Hpre  = (const float*)d_in[2];
    const float* Hpost = (const float*)d_in[3];
    f4* out = (f4*)d_out;

    // ND4/256 = 2048 blocks; each thread handles one r across 4 batches.
    hc_mix_kernel<<<ND4 / 256, 256, 0, stream>>>(in, out, Hres, Hpre, Hpost);
}